// Round 4
// baseline (154.866 us; speedup 1.0000x reference)
//
#include <hip/hip_runtime.h>
#include <math.h>

#define HW 384
#define PLANE (HW*HW)   // 147456

// ---- workspace layout (float-index offsets) ----
#define WT1_OFF   0                         // 7200 floats: [c*25+tap][32 o]
#define SC1_OFF   7296                      // 32
#define SH1_OFF   7328                      // 32
#define WT2_OFF   7360                      // 6400: [ci*25+tap][8 o]
#define SC2_OFF   13760                     // 8
#define SH2_OFF   13768                     // 8
#define W3_OFF    13776                     // 200: [ci*25+tap]
#define SC3_OFF   13976                     // 1
#define SH3_OFF   13977                     // 1
#define FWT_OFF   13984                     // 5488: [(dz*7+dy)*7+dx][c*4+o]
#define H1_OFF    32768                     // 32*PLANE
#define H2_OFF    (32768 + 32*PLANE)        // 8*PLANE
#define DEPTH_OFF (32768 + 40*PLANE)        // PLANE int32

// ---------------- prep: fold BN, transpose weights (multi-block) ----------------
__global__ void prep_kernel(
    const float* __restrict__ c1w, const float* __restrict__ c1b,
    const float* __restrict__ g1, const float* __restrict__ b1,
    const float* __restrict__ m1, const float* __restrict__ v1,
    const float* __restrict__ c2w, const float* __restrict__ c2b,
    const float* __restrict__ g2, const float* __restrict__ b2,
    const float* __restrict__ m2, const float* __restrict__ v2,
    const float* __restrict__ c3w, const float* __restrict__ c3b,
    const float* __restrict__ g3, const float* __restrict__ b3,
    const float* __restrict__ m3, const float* __restrict__ v3,
    const float* __restrict__ fw, float* __restrict__ W)
{
    int gid = blockIdx.x * 256 + threadIdx.x;
    int gstr = gridDim.x * 256;
    for (int i = gid; i < 7200; i += gstr) {
        int o = i & 31, ct = i >> 5;
        W[WT1_OFF + i] = c1w[o * 225 + ct];
    }
    for (int i = gid; i < 6400; i += gstr) {
        int o = i & 7, ct = i >> 3;
        W[WT2_OFF + i] = c2w[o * 800 + ct];
    }
    for (int i = gid; i < 5488; i += gstr) {
        int s = i >> 4, r = i & 15, c = r >> 2, o = r & 3;
        W[FWT_OFF + i] = fw[o * 1372 + c * 343 + s];
    }
    if (blockIdx.x == 0) {
        int tid = threadIdx.x;
        if (tid < 32) {
            float sc = g1[tid] / sqrtf(v1[tid] + 1e-5f);
            W[SC1_OFF + tid] = sc;
            W[SH1_OFF + tid] = (c1b[tid] - m1[tid]) * sc + b1[tid];
        }
        if (tid < 8) {
            float sc = g2[tid] / sqrtf(v2[tid] + 1e-5f);
            W[SC2_OFF + tid] = sc;
            W[SH2_OFF + tid] = (c2b[tid] - m2[tid]) * sc + b2[tid];
        }
        if (tid < 200) W[W3_OFF + tid] = c3w[tid];
        if (tid == 0) {
            float sc = g3[0] / sqrtf(v3[0] + 1e-5f);
            W[SC3_OFF] = sc;
            W[SH3_OFF] = (c3b[0] - m3[0]) * sc + b3[0];
        }
    }
}

// Load 12 floats (3 aligned float4) of row r covering x = xb..xb+11, zero-masked.
__device__ __forceinline__ void load_row12(const float* __restrict__ plane,
                                           int r, int xb, bool rok, float* rowf)
{
#pragma unroll
    for (int k = 0; k < 3; ++k) {
        int x = xb + 4 * k;
        float4 v = make_float4(0.f, 0.f, 0.f, 0.f);
        if (rok && x >= 0 && x < HW) v = *(const float4*)(plane + r * HW + x);
        rowf[4 * k + 0] = v.x; rowf[4 * k + 1] = v.y;
        rowf[4 * k + 2] = v.z; rowf[4 * k + 3] = v.w;
    }
}

// ---------------- conv1: 9 -> 32, 5x5, BN+ReLU ----------------
// 256 thr = 4 waves (output-channel groups of 8) x 64 quad slots.
// No LDS, no barriers: pixels read direct from global (L1/L2), quad of 4 px.
__global__ __launch_bounds__(256, 2) void conv1_kernel(
    const float* __restrict__ light, const float* __restrict__ albedo,
    const float* __restrict__ normals, const float* __restrict__ W,
    float* __restrict__ h1)
{
    int tid = threadIdx.x;
    int og = tid >> 6;            // output group (wave id)
    int slot = tid & 63;
    int qx = slot & 7, ty = slot >> 3;
    int bx = blockIdx.x % 12, by = blockIdx.x / 12;
    int x0 = bx * 32, y0 = by * 8;
    int xb = x0 + 4 * qx - 4;

    float acc[8][4];
#pragma unroll
    for (int o = 0; o < 8; ++o)
#pragma unroll
        for (int j = 0; j < 4; ++j) acc[o][j] = 0.f;

    const float* wb = W + WT1_OFF + og * 8;   // [ct][32o]
#pragma unroll 1
    for (int c = 0; c < 9; ++c) {
        const float* plane = (c < 3) ? (light + c * PLANE)
                           : (c < 6) ? (albedo + (c - 3) * PLANE)
                                     : (normals + (c - 6) * PLANE);
        const float* wc = wb + c * 25 * 32;
#pragma unroll
        for (int ky = 0; ky < 5; ++ky) {
            int r = y0 + ty + ky - 2;
            bool rok = ((unsigned)r < (unsigned)HW);
            float rowf[12];
            load_row12(plane, r, xb, rok, rowf);
#pragma unroll
            for (int kx = 0; kx < 5; ++kx) {
                float4 wA = *(const float4*)(wc + (ky * 5 + kx) * 32);
                float4 wB = *(const float4*)(wc + (ky * 5 + kx) * 32 + 4);
#pragma unroll
                for (int j = 0; j < 4; ++j) {
                    float v = rowf[2 + kx + j];
                    acc[0][j] = fmaf(v, wA.x, acc[0][j]);
                    acc[1][j] = fmaf(v, wA.y, acc[1][j]);
                    acc[2][j] = fmaf(v, wA.z, acc[2][j]);
                    acc[3][j] = fmaf(v, wA.w, acc[3][j]);
                    acc[4][j] = fmaf(v, wB.x, acc[4][j]);
                    acc[5][j] = fmaf(v, wB.y, acc[5][j]);
                    acc[6][j] = fmaf(v, wB.z, acc[6][j]);
                    acc[7][j] = fmaf(v, wB.w, acc[7][j]);
                }
            }
        }
    }

    int pix = (y0 + ty) * HW + x0 + qx * 4;
#pragma unroll
    for (int o = 0; o < 8; ++o) {
        int oc = og * 8 + o;
        float sc = W[SC1_OFF + oc], sh = W[SH1_OFF + oc];
        float4 rv;
        rv.x = fmaxf(fmaf(acc[o][0], sc, sh), 0.f);
        rv.y = fmaxf(fmaf(acc[o][1], sc, sh), 0.f);
        rv.z = fmaxf(fmaf(acc[o][2], sc, sh), 0.f);
        rv.w = fmaxf(fmaf(acc[o][3], sc, sh), 0.f);
        *(float4*)&h1[oc * PLANE + pix] = rv;
    }
}

// ---------------- conv2: 32 -> 8, 5x5, BN+ReLU ----------------
// 4 waves split input channels (8 each); pixels direct from global; one
// barrier; all-wave LDS reduction (wave w combines output planes 2w,2w+1).
__global__ __launch_bounds__(256, 2) void conv2_kernel(
    const float* __restrict__ h1, const float* __restrict__ W,
    float* __restrict__ h2)
{
    __shared__ __align__(16) float red[4 * 64 * 36];   // 36.9 KB
    int tid = threadIdx.x;
    int cg = tid >> 6;            // input-channel group (wave id)
    int slot = tid & 63;
    int qx = slot & 7, ty = slot >> 3;
    int bx = blockIdx.x % 12, by = blockIdx.x / 12;
    int x0 = bx * 32, y0 = by * 8;
    int xb = x0 + 4 * qx - 4;

    float acc[8][4];
#pragma unroll
    for (int o = 0; o < 8; ++o)
#pragma unroll
        for (int j = 0; j < 4; ++j) acc[o][j] = 0.f;

    const float* wb = W + WT2_OFF;
#pragma unroll 1
    for (int cc = 0; cc < 8; ++cc) {
        int c = cg * 8 + cc;
        const float* plane = h1 + c * PLANE;
        const float* wc = wb + c * 200;
#pragma unroll
        for (int ky = 0; ky < 5; ++ky) {
            int r = y0 + ty + ky - 2;
            bool rok = ((unsigned)r < (unsigned)HW);
            float rowf[12];
            load_row12(plane, r, xb, rok, rowf);
#pragma unroll
            for (int kx = 0; kx < 5; ++kx) {
                float4 wA = *(const float4*)(wc + (ky * 5 + kx) * 8);
                float4 wB = *(const float4*)(wc + (ky * 5 + kx) * 8 + 4);
#pragma unroll
                for (int j = 0; j < 4; ++j) {
                    float v = rowf[2 + kx + j];
                    acc[0][j] = fmaf(v, wA.x, acc[0][j]);
                    acc[1][j] = fmaf(v, wA.y, acc[1][j]);
                    acc[2][j] = fmaf(v, wA.z, acc[2][j]);
                    acc[3][j] = fmaf(v, wA.w, acc[3][j]);
                    acc[4][j] = fmaf(v, wB.x, acc[4][j]);
                    acc[5][j] = fmaf(v, wB.y, acc[5][j]);
                    acc[6][j] = fmaf(v, wB.z, acc[6][j]);
                    acc[7][j] = fmaf(v, wB.w, acc[7][j]);
                }
            }
        }
    }

    // partials: [cg][slot][8o][4px], row stride 36 floats
    float* pp = red + (cg * 64 + slot) * 36;
#pragma unroll
    for (int o = 0; o < 8; ++o)
        *(float4*)(pp + o * 4) = make_float4(acc[o][0], acc[o][1], acc[o][2], acc[o][3]);
    __syncthreads();

    // wave w reduces output planes {2w, 2w+1} over all 64 slots
    int w = cg;
    float4 s0 = make_float4(0.f, 0.f, 0.f, 0.f);
    float4 s1 = make_float4(0.f, 0.f, 0.f, 0.f);
#pragma unroll
    for (int g = 0; g < 4; ++g) {
        const float* q = red + (g * 64 + slot) * 36 + w * 8;
        float4 t0 = *(const float4*)q;
        float4 t1 = *(const float4*)(q + 4);
        s0.x += t0.x; s0.y += t0.y; s0.z += t0.z; s0.w += t0.w;
        s1.x += t1.x; s1.y += t1.y; s1.z += t1.z; s1.w += t1.w;
    }
    int o0 = 2 * w, o1 = 2 * w + 1;
    float sc0 = W[SC2_OFF + o0], sh0 = W[SH2_OFF + o0];
    float sc1 = W[SC2_OFF + o1], sh1 = W[SH2_OFF + o1];
    float4 r0, r1;
    r0.x = fmaxf(fmaf(s0.x, sc0, sh0), 0.f);
    r0.y = fmaxf(fmaf(s0.y, sc0, sh0), 0.f);
    r0.z = fmaxf(fmaf(s0.z, sc0, sh0), 0.f);
    r0.w = fmaxf(fmaf(s0.w, sc0, sh0), 0.f);
    r1.x = fmaxf(fmaf(s1.x, sc1, sh1), 0.f);
    r1.y = fmaxf(fmaf(s1.y, sc1, sh1), 0.f);
    r1.z = fmaxf(fmaf(s1.z, sc1, sh1), 0.f);
    r1.w = fmaxf(fmaf(s1.w, sc1, sh1), 0.f);
    int pix = (y0 + ty) * HW + x0 + qx * 4;
    *(float4*)&h2[o0 * PLANE + pix] = r0;
    *(float4*)&h2[o1 * PLANE + pix] = r1;
}

// ---------------- conv3: 8 -> 1, 5x5, BN + sigmoid + floor -> depth ----------------
__global__ __launch_bounds__(256) void conv3_kernel(
    const float* __restrict__ h2, const float* __restrict__ W,
    int* __restrict__ depth)
{
    __shared__ float tile[8][12][36];
    int tid = threadIdx.x;
    int tx = tid & 31, ty = tid >> 5;
    int bx = blockIdx.x % 12, by = blockIdx.x / 12;
    int x0 = bx * 32 - 2, y0 = by * 8 - 2;

    for (int p = tid; p < 432; p += 256) {
        int py = p / 36, px = p % 36;
        int gy = y0 + py, gx = x0 + px;
        bool ok = ((unsigned)gy < (unsigned)HW) && ((unsigned)gx < (unsigned)HW);
        int gofs = ok ? (gy * HW + gx) : 0;
#pragma unroll
        for (int c = 0; c < 8; ++c) {
            float v = h2[c * PLANE + gofs];
            tile[c][py][px] = ok ? v : 0.f;
        }
    }
    __syncthreads();

    float a = 0.f;
#pragma unroll 1
    for (int c = 0; c < 8; ++c) {
#pragma unroll
        for (int ky = 0; ky < 5; ++ky) {
#pragma unroll
            for (int kx = 0; kx < 5; ++kx) {
                a = fmaf(tile[c][ty + ky][tx + kx], W[W3_OFF + (c * 5 + ky) * 5 + kx], a);
            }
        }
    }
    float y = fmaf(a, W[SC3_OFF], W[SH3_OFF]);
    float s = 1.f / (1.f + expf(-y));
    int d = (int)floorf(s * (16.f - 1e-5f));

    int gy = by * 8 + ty, gx = bx * 32 + tx;
    depth[gy * HW + gx] = d;
}

// ---------------- final: sparse 3d conv gather + divide + albedo ----------------
__global__ __launch_bounds__(256) void final_kernel(
    const float* __restrict__ light, const float* __restrict__ albedo,
    const float* __restrict__ W, const float* __restrict__ fb,
    float* __restrict__ out)
{
    __shared__ float fw[5488];
    __shared__ float ltile[3][14][38];
    __shared__ int   dtile[14][38];

    int tid = threadIdx.x;
    int tx = tid & 31, ty = tid >> 5;
    int bx = blockIdx.x % 12, by = blockIdx.x / 12;
    int x0 = bx * 32 - 3, y0 = by * 8 - 3;

    for (int i = tid; i < 5488; i += 256) fw[i] = W[FWT_OFF + i];

    const int* dmap = ((const int*)W) + DEPTH_OFF;
    for (int p = tid; p < 14 * 38; p += 256) {
        int py = p / 38, px = p % 38;
        int gy = y0 + py, gx = x0 + px;
        bool ok = ((unsigned)gy < (unsigned)HW) && ((unsigned)gx < (unsigned)HW);
        int gofs = ok ? (gy * HW + gx) : 0;
        int dv = dmap[gofs];
        dtile[py][px] = ok ? dv : -1000;
#pragma unroll
        for (int c = 0; c < 3; ++c) {
            float lv = light[c * PLANE + gofs];
            ltile[c][py][px] = ok ? lv : 0.f;
        }
    }
    __syncthreads();

    int d0 = dtile[ty + 3][tx + 3];
    float a0 = fb[0], a1 = fb[1], a2 = fb[2], a3 = fb[3];
    const float4* fw4 = (const float4*)fw;

#pragma unroll 1
    for (int dy = 0; dy < 7; ++dy) {
#pragma unroll
        for (int dx = 0; dx < 7; ++dx) {
            int dd = dtile[ty + dy][tx + dx];
            int dz = dd - d0 + 3;
            if ((unsigned)dz < 7u) {
                int s = (dz * 7 + dy) * 7 + dx;
                float4 w0 = fw4[s * 4 + 0];
                float4 w1 = fw4[s * 4 + 1];
                float4 w2 = fw4[s * 4 + 2];
                float4 w3 = fw4[s * 4 + 3];
                float l0 = ltile[0][ty + dy][tx + dx];
                float l1 = ltile[1][ty + dy][tx + dx];
                float l2 = ltile[2][ty + dy][tx + dx];
                a0 += l0 * w0.x + l1 * w1.x + l2 * w2.x + w3.x;
                a1 += l0 * w0.y + l1 * w1.y + l2 * w2.y + w3.y;
                a2 += l0 * w0.z + l1 * w1.z + l2 * w2.z + w3.z;
                a3 += l0 * w0.w + l1 * w1.w + l2 * w2.w + w3.w;
            }
        }
    }

    int gy = by * 8 + ty, gx = bx * 32 + tx;
    int pix = gy * HW + gx;
    out[0 * PLANE + pix] = a0 / a3 * albedo[0 * PLANE + pix];
    out[1 * PLANE + pix] = a1 / a3 * albedo[1 * PLANE + pix];
    out[2 * PLANE + pix] = a2 / a3 * albedo[2 * PLANE + pix];
}

extern "C" void kernel_launch(void* const* d_in, const int* in_sizes, int n_in,
                              void* d_out, int out_size, void* d_ws, size_t ws_size,
                              hipStream_t stream) {
    const float* light     = (const float*)d_in[0];
    const float* albedo    = (const float*)d_in[1];
    const float* normals   = (const float*)d_in[2];
    const float* c1_w = (const float*)d_in[4];
    const float* c1_b = (const float*)d_in[5];
    const float* bn1_g = (const float*)d_in[6];
    const float* bn1_b = (const float*)d_in[7];
    const float* bn1_m = (const float*)d_in[8];
    const float* bn1_v = (const float*)d_in[9];
    const float* c2_w = (const float*)d_in[10];
    const float* c2_b = (const float*)d_in[11];
    const float* bn2_g = (const float*)d_in[12];
    const float* bn2_b = (const float*)d_in[13];
    const float* bn2_m = (const float*)d_in[14];
    const float* bn2_v = (const float*)d_in[15];
    const float* c3_w = (const float*)d_in[16];
    const float* c3_b = (const float*)d_in[17];
    const float* bn3_g = (const float*)d_in[18];
    const float* bn3_b = (const float*)d_in[19];
    const float* bn3_m = (const float*)d_in[20];
    const float* bn3_v = (const float*)d_in[21];
    const float* f_w = (const float*)d_in[22];
    const float* f_b = (const float*)d_in[23];

    float* W = (float*)d_ws;
    float* h1 = W + H1_OFF;
    float* h2 = W + H2_OFF;
    int* depth = ((int*)d_ws) + DEPTH_OFF;
    float* out = (float*)d_out;

    hipLaunchKernelGGL(prep_kernel, dim3(16), dim3(256), 0, stream,
                       c1_w, c1_b, bn1_g, bn1_b, bn1_m, bn1_v,
                       c2_w, c2_b, bn2_g, bn2_b, bn2_m, bn2_v,
                       c3_w, c3_b, bn3_g, bn3_b, bn3_m, bn3_v,
                       f_w, W);
    hipLaunchKernelGGL(conv1_kernel, dim3(576), dim3(256), 0, stream,
                       light, albedo, normals, W, h1);
    hipLaunchKernelGGL(conv2_kernel, dim3(576), dim3(256), 0, stream,
                       h1, W, h2);
    hipLaunchKernelGGL(conv3_kernel, dim3(576), dim3(256), 0, stream,
                       h2, W, depth);
    hipLaunchKernelGGL(final_kernel, dim3(576), dim3(256), 0, stream,
                       light, albedo, W, f_b, out);
}

// Round 5
// 144.593 us; speedup vs baseline: 1.0710x; 1.0710x over previous
//
#include <hip/hip_runtime.h>
#include <math.h>

#define HW 384
#define PLANE (HW*HW)   // 147456

// ---- workspace layout (float-index offsets) ----
#define WT1_OFF   0                         // 7200: [ct][32 o]
#define SC1_OFF   7296                      // 32
#define SH1_OFF   7328                      // 32
#define WT2_OFF   7360                      // 6400: [c*25+tap][8 o]
#define SC2_OFF   13760                     // 8
#define SH2_OFF   13768                     // 8
#define W3_OFF    13776                     // 200
#define SC3_OFF   13976                     // 1
#define SH3_OFF   13977                     // 1
#define FWT_OFF   13984                     // 5488: [k=o*4+c][s]  (k*343+s)
#define H1_OFF    32768                     // 32*PLANE
#define H2_OFF    (32768 + 32*PLANE)        // 16*PLANE (two 8-plane partial halves)
#define DEPTH_OFF (32768 + 48*PLANE)        // PLANE int32

// ---------------- prep ----------------
__global__ void prep_kernel(
    const float* __restrict__ c1w, const float* __restrict__ c1b,
    const float* __restrict__ g1, const float* __restrict__ b1,
    const float* __restrict__ m1, const float* __restrict__ v1,
    const float* __restrict__ c2w, const float* __restrict__ c2b,
    const float* __restrict__ g2, const float* __restrict__ b2,
    const float* __restrict__ m2, const float* __restrict__ v2,
    const float* __restrict__ c3w, const float* __restrict__ c3b,
    const float* __restrict__ g3, const float* __restrict__ b3,
    const float* __restrict__ m3, const float* __restrict__ v3,
    const float* __restrict__ fw, float* __restrict__ W)
{
    int gid = blockIdx.x * 256 + threadIdx.x;
    int gstr = gridDim.x * 256;
    for (int i = gid; i < 7200; i += gstr) {
        int o = i & 31, ct = i >> 5;
        W[WT1_OFF + i] = c1w[o * 225 + ct];
    }
    for (int i = gid; i < 6400; i += gstr) {
        int o = i & 7, ct = i >> 3;
        W[WT2_OFF + i] = c2w[o * 800 + ct];
    }
    // f_w: OIDHW (4,4,7,7,7) -> [k=o*4+c][s]
    for (int i = gid; i < 5488; i += gstr) {
        int k = i / 343, s = i - k * 343;
        int o = k >> 2, c = k & 3;
        W[FWT_OFF + i] = fw[o * 1372 + c * 343 + s];
    }
    if (blockIdx.x == 0) {
        int tid = threadIdx.x;
        if (tid < 32) {
            float sc = g1[tid] / sqrtf(v1[tid] + 1e-5f);
            W[SC1_OFF + tid] = sc;
            W[SH1_OFF + tid] = (c1b[tid] - m1[tid]) * sc + b1[tid];
        }
        if (tid < 8) {
            float sc = g2[tid] / sqrtf(v2[tid] + 1e-5f);
            W[SC2_OFF + tid] = sc;
            W[SH2_OFF + tid] = (c2b[tid] - m2[tid]) * sc + b2[tid];
        }
        if (tid < 200) W[W3_OFF + tid] = c3w[tid];
        if (tid == 0) {
            float sc = g3[0] / sqrtf(v3[0] + 1e-5f);
            W[SC3_OFF] = sc;
            W[SH3_OFF] = (c3b[0] - m3[0]) * sc + b3[0];
        }
    }
}

// ---------------- conv1: 9 -> 32, 5x5, BN+ReLU ----------------
// grid 1152 = 576 spatial x 2 output-halves. 4 waves x 4 outs, quad px,
// ds_read_b128 row reads. No inter-wave interaction.
__global__ __launch_bounds__(256, 4) void conv1_kernel(
    const float* __restrict__ light, const float* __restrict__ albedo,
    const float* __restrict__ normals, const float* __restrict__ W,
    float* __restrict__ h1)
{
    __shared__ __align__(16) float tile[9][12][36];   // 15.6 KB
    int tid = threadIdx.x;
    int w = tid >> 6, slot = tid & 63;
    int qx = slot & 7, ty = slot >> 3;
    int bid = blockIdx.x;
    int half = bid & 1, sp = bid >> 1;
    int bx = sp % 12, by = sp / 12;
    int x0 = bx * 32, y0 = by * 8;

    for (int p = tid; p < 432; p += 256) {
        int py = p / 36, px = p % 36;
        int gy = y0 + py - 2, gx = x0 + px - 2;
        bool ok = ((unsigned)gy < (unsigned)HW) && ((unsigned)gx < (unsigned)HW);
        int gofs = ok ? (gy * HW + gx) : 0;
#pragma unroll
        for (int c = 0; c < 3; ++c) {
            float a = light[c * PLANE + gofs];
            float b = albedo[c * PLANE + gofs];
            float n = normals[c * PLANE + gofs];
            tile[c][py][px]     = ok ? a : 0.f;
            tile[c + 3][py][px] = ok ? b : 0.f;
            tile[c + 6][py][px] = ok ? n : 0.f;
        }
    }
    __syncthreads();

    float acc[4][4];
#pragma unroll
    for (int o = 0; o < 4; ++o)
#pragma unroll
        for (int j = 0; j < 4; ++j) acc[o][j] = 0.f;

    const float* wb = W + WT1_OFF + half * 16 + w * 4;   // [ct][32]
#pragma unroll 1
    for (int c = 0; c < 9; ++c) {
        const float* bc = &tile[c][0][0];
        const float* wc = wb + c * 25 * 32;
#pragma unroll
        for (int ky = 0; ky < 5; ++ky) {
            const float* rp = bc + (ty + ky) * 36 + qx * 4;
            float4 ra = *(const float4*)rp;
            float4 rb = *(const float4*)(rp + 4);
            float row[8] = {ra.x, ra.y, ra.z, ra.w, rb.x, rb.y, rb.z, rb.w};
#pragma unroll
            for (int kx = 0; kx < 5; ++kx) {
                float4 wv = *(const float4*)(wc + (ky * 5 + kx) * 32);
#pragma unroll
                for (int j = 0; j < 4; ++j) {
                    float v = row[kx + j];
                    acc[0][j] = fmaf(v, wv.x, acc[0][j]);
                    acc[1][j] = fmaf(v, wv.y, acc[1][j]);
                    acc[2][j] = fmaf(v, wv.z, acc[2][j]);
                    acc[3][j] = fmaf(v, wv.w, acc[3][j]);
                }
            }
        }
    }

    int pix = (y0 + ty) * HW + x0 + qx * 4;
#pragma unroll
    for (int o = 0; o < 4; ++o) {
        int oc = half * 16 + w * 4 + o;
        float sc = W[SC1_OFF + oc], sh = W[SH1_OFF + oc];
        float4 rv;
        rv.x = fmaxf(fmaf(acc[o][0], sc, sh), 0.f);
        rv.y = fmaxf(fmaf(acc[o][1], sc, sh), 0.f);
        rv.z = fmaxf(fmaf(acc[o][2], sc, sh), 0.f);
        rv.w = fmaxf(fmaf(acc[o][3], sc, sh), 0.f);
        *(float4*)&h1[oc * PLANE + pix] = rv;
    }
}

__device__ __forceinline__ void stage8(float* dst, const float* __restrict__ src,
                                       int p0, int gofs0, bool ok0,
                                       int p1, int gofs1, bool ok1, bool has1)
{
#pragma unroll
    for (int c = 0; c < 8; ++c) {
        float v = src[c * PLANE + gofs0];
        dst[c * 432 + p0] = ok0 ? v : 0.f;
    }
    if (has1) {
#pragma unroll
        for (int c = 0; c < 8; ++c) {
            float v = src[c * PLANE + gofs1];
            dst[c * 432 + p1] = ok1 ? v : 0.f;
        }
    }
}

// ---------------- conv2: 32 -> 8, 5x5 -> raw partials ----------------
// grid 1152 = 576 spatial x 2 input-halves (16 ch each). 4 waves x 2 outs.
// Chunked (8ch) double-buffered LDS, quad px + b128 reads. No BN here.
__global__ __launch_bounds__(256, 4) void conv2_kernel(
    const float* __restrict__ h1, const float* __restrict__ W,
    float* __restrict__ h2p)
{
    __shared__ __align__(16) float tile[2][8][12][36];   // 27.6 KB
    int tid = threadIdx.x;
    int w = tid >> 6, slot = tid & 63;
    int qx = slot & 7, ty = slot >> 3;
    int bid = blockIdx.x;
    int half = bid & 1, sp = bid >> 1;
    int bx = sp % 12, by = sp / 12;
    int x0 = bx * 32, y0 = by * 8;
    int cbase = half * 16;

    int p0 = tid;
    int py0 = p0 / 36, px0 = p0 % 36;
    int gy0 = y0 + py0 - 2, gx0 = x0 + px0 - 2;
    bool ok0 = ((unsigned)gy0 < (unsigned)HW) && ((unsigned)gx0 < (unsigned)HW);
    int gofs0 = ok0 ? (gy0 * HW + gx0) : 0;

    int p1 = tid + 256;
    bool has1 = (p1 < 432);
    int py1 = p1 / 36, px1 = p1 % 36;
    int gy1 = y0 + py1 - 2, gx1 = x0 + px1 - 2;
    bool ok1 = has1 && ((unsigned)gy1 < (unsigned)HW) && ((unsigned)gx1 < (unsigned)HW);
    int gofs1 = ok1 ? (gy1 * HW + gx1) : 0;

    stage8(&tile[0][0][0][0], h1 + cbase * PLANE, p0, gofs0, ok0, p1, gofs1, ok1, has1);
    __syncthreads();

    float acc[2][4];
#pragma unroll
    for (int o = 0; o < 2; ++o)
#pragma unroll
        for (int j = 0; j < 4; ++j) acc[o][j] = 0.f;

#pragma unroll 1
    for (int k = 0; k < 2; ++k) {
        if (k == 0)
            stage8(&tile[1][0][0][0], h1 + (cbase + 8) * PLANE,
                   p0, gofs0, ok0, p1, gofs1, ok1, has1);

        const float* buf = &tile[k][0][0][0];
        const float* wc = W + WT2_OFF + (cbase + k * 8) * 200 + 2 * w;
#pragma unroll 1
        for (int cc = 0; cc < 8; ++cc) {
            const float* bc = buf + cc * 432;
            const float* wt = wc + cc * 200;
#pragma unroll
            for (int ky = 0; ky < 5; ++ky) {
                const float* rp = bc + (ty + ky) * 36 + qx * 4;
                float4 ra = *(const float4*)rp;
                float4 rb = *(const float4*)(rp + 4);
                float row[8] = {ra.x, ra.y, ra.z, ra.w, rb.x, rb.y, rb.z, rb.w};
#pragma unroll
                for (int kx = 0; kx < 5; ++kx) {
                    float2 wv = *(const float2*)(wt + (ky * 5 + kx) * 8);
#pragma unroll
                    for (int j = 0; j < 4; ++j) {
                        float v = row[kx + j];
                        acc[0][j] = fmaf(v, wv.x, acc[0][j]);
                        acc[1][j] = fmaf(v, wv.y, acc[1][j]);
                    }
                }
            }
        }
        if (k == 0) __syncthreads();
    }

    int pix = (y0 + ty) * HW + x0 + qx * 4;
    float* dst = h2p + half * 8 * PLANE;
#pragma unroll
    for (int o = 0; o < 2; ++o) {
        int oc = 2 * w + o;
        *(float4*)&dst[oc * PLANE + pix] =
            make_float4(acc[o][0], acc[o][1], acc[o][2], acc[o][3]);
    }
}

// ---------------- conv3: combine halves + BN+ReLU, 8 -> 1, sigmoid, floor ----------------
__global__ __launch_bounds__(256, 2) void conv3_kernel(
    const float* __restrict__ h2p, const float* __restrict__ W,
    int* __restrict__ depth)
{
    __shared__ float tile[8][12][36];
    int tid = threadIdx.x;
    int tx = tid & 31, ty = tid >> 5;
    int bx = blockIdx.x % 12, by = blockIdx.x / 12;
    int x0 = bx * 32 - 2, y0 = by * 8 - 2;

    for (int p = tid; p < 432; p += 256) {
        int py = p / 36, px = p % 36;
        int gy = y0 + py, gx = x0 + px;
        bool ok = ((unsigned)gy < (unsigned)HW) && ((unsigned)gx < (unsigned)HW);
        int gofs = ok ? (gy * HW + gx) : 0;
#pragma unroll
        for (int c = 0; c < 8; ++c) {
            float t = h2p[c * PLANE + gofs] + h2p[(c + 8) * PLANE + gofs];
            float r = fmaxf(fmaf(t, W[SC2_OFF + c], W[SH2_OFF + c]), 0.f);
            tile[c][py][px] = ok ? r : 0.f;
        }
    }
    __syncthreads();

    float a = 0.f;
#pragma unroll 1
    for (int c = 0; c < 8; ++c) {
#pragma unroll
        for (int ky = 0; ky < 5; ++ky) {
#pragma unroll
            for (int kx = 0; kx < 5; ++kx) {
                a = fmaf(tile[c][ty + ky][tx + kx], W[W3_OFF + (c * 5 + ky) * 5 + kx], a);
            }
        }
    }
    float y = fmaf(a, W[SC3_OFF], W[SH3_OFF]);
    float s = 1.f / (1.f + expf(-y));
    int d = (int)floorf(s * (16.f - 1e-5f));

    int gy = by * 8 + ty, gx = bx * 32 + tx;
    depth[gy * HW + gx] = d;
}

// ---------------- final: sparse 3d conv gather + divide + albedo ----------------
__global__ __launch_bounds__(256, 2) void final_kernel(
    const float* __restrict__ light, const float* __restrict__ albedo,
    const float* __restrict__ W, const float* __restrict__ fb,
    float* __restrict__ out)
{
    __shared__ float fwl[343 * 17];            // [s][k], stride 17 kills dz-bank pileups
    __shared__ float ltile[3][14][38];
    __shared__ int   dtile[14][38];

    int tid = threadIdx.x;
    int tx = tid & 31, ty = tid >> 5;
    int bx = blockIdx.x % 12, by = blockIdx.x / 12;
    int x0 = bx * 32 - 3, y0 = by * 8 - 3;

    for (int i = tid; i < 5488; i += 256) {
        int k = i / 343, s = i - k * 343;
        fwl[s * 17 + k] = W[FWT_OFF + i];
    }

    const int* dmap = ((const int*)W) + DEPTH_OFF;
    for (int p = tid; p < 14 * 38; p += 256) {
        int py = p / 38, px = p % 38;
        int gy = y0 + py, gx = x0 + px;
        bool ok = ((unsigned)gy < (unsigned)HW) && ((unsigned)gx < (unsigned)HW);
        int gofs = ok ? (gy * HW + gx) : 0;
        int dv = dmap[gofs];
        dtile[py][px] = ok ? dv : -1000;
#pragma unroll
        for (int c = 0; c < 3; ++c) {
            float lv = light[c * PLANE + gofs];
            ltile[c][py][px] = ok ? lv : 0.f;
        }
    }
    __syncthreads();

    int d0 = dtile[ty + 3][tx + 3];
    float a0 = fb[0], a1 = fb[1], a2 = fb[2], a3 = fb[3];

#pragma unroll 1
    for (int dy = 0; dy < 7; ++dy) {
#pragma unroll
        for (int dx = 0; dx < 7; ++dx) {
            int dd = dtile[ty + dy][tx + dx];
            int dz = dd - d0 + 3;
            if ((unsigned)dz < 7u) {
                int s = (dz * 7 + dy) * 7 + dx;
                const float* fs = fwl + s * 17;   // k = o*4 + c
                float l0 = ltile[0][ty + dy][tx + dx];
                float l1 = ltile[1][ty + dy][tx + dx];
                float l2 = ltile[2][ty + dy][tx + dx];
                a0 += l0 * fs[0]  + l1 * fs[1]  + l2 * fs[2]  + fs[3];
                a1 += l0 * fs[4]  + l1 * fs[5]  + l2 * fs[6]  + fs[7];
                a2 += l0 * fs[8]  + l1 * fs[9]  + l2 * fs[10] + fs[11];
                a3 += l0 * fs[12] + l1 * fs[13] + l2 * fs[14] + fs[15];
            }
        }
    }

    int gy = by * 8 + ty, gx = bx * 32 + tx;
    int pix = gy * HW + gx;
    out[0 * PLANE + pix] = a0 / a3 * albedo[0 * PLANE + pix];
    out[1 * PLANE + pix] = a1 / a3 * albedo[1 * PLANE + pix];
    out[2 * PLANE + pix] = a2 / a3 * albedo[2 * PLANE + pix];
}

extern "C" void kernel_launch(void* const* d_in, const int* in_sizes, int n_in,
                              void* d_out, int out_size, void* d_ws, size_t ws_size,
                              hipStream_t stream) {
    const float* light     = (const float*)d_in[0];
    const float* albedo    = (const float*)d_in[1];
    const float* normals   = (const float*)d_in[2];
    const float* c1_w = (const float*)d_in[4];
    const float* c1_b = (const float*)d_in[5];
    const float* bn1_g = (const float*)d_in[6];
    const float* bn1_b = (const float*)d_in[7];
    const float* bn1_m = (const float*)d_in[8];
    const float* bn1_v = (const float*)d_in[9];
    const float* c2_w = (const float*)d_in[10];
    const float* c2_b = (const float*)d_in[11];
    const float* bn2_g = (const float*)d_in[12];
    const float* bn2_b = (const float*)d_in[13];
    const float* bn2_m = (const float*)d_in[14];
    const float* bn2_v = (const float*)d_in[15];
    const float* c3_w = (const float*)d_in[16];
    const float* c3_b = (const float*)d_in[17];
    const float* bn3_g = (const float*)d_in[18];
    const float* bn3_b = (const float*)d_in[19];
    const float* bn3_m = (const float*)d_in[20];
    const float* bn3_v = (const float*)d_in[21];
    const float* f_w = (const float*)d_in[22];
    const float* f_b = (const float*)d_in[23];

    float* W = (float*)d_ws;
    float* h1 = W + H1_OFF;
    float* h2p = W + H2_OFF;
    int* depth = ((int*)d_ws) + DEPTH_OFF;
    float* out = (float*)d_out;

    hipLaunchKernelGGL(prep_kernel, dim3(16), dim3(256), 0, stream,
                       c1_w, c1_b, bn1_g, bn1_b, bn1_m, bn1_v,
                       c2_w, c2_b, bn2_g, bn2_b, bn2_m, bn2_v,
                       c3_w, c3_b, bn3_g, bn3_b, bn3_m, bn3_v,
                       f_w, W);
    hipLaunchKernelGGL(conv1_kernel, dim3(1152), dim3(256), 0, stream,
                       light, albedo, normals, W, h1);
    hipLaunchKernelGGL(conv2_kernel, dim3(1152), dim3(256), 0, stream,
                       h1, W, h2p);
    hipLaunchKernelGGL(conv3_kernel, dim3(576), dim3(256), 0, stream,
                       h2p, W, depth);
    hipLaunchKernelGGL(final_kernel, dim3(576), dim3(256), 0, stream,
                       light, albedo, W, f_b, out);
}